// Round 6
// baseline (1044.181 us; speedup 1.0000x reference)
//
#include <hip/hip_runtime.h>
#include <math.h>

// Problem constants (fixed by the reference)
#define BN 16384
#define DN 512
#define KN 16384
#define HN 256
#define ZN 128

#define EPS_G 0.02f   // >= 2x worst-case bf16-split score error (~8e-3)

typedef short short8 __attribute__((ext_vector_type(8)));
typedef short short4v __attribute__((ext_vector_type(4)));
typedef float f32x4 __attribute__((ext_vector_type(4)));

__device__ __forceinline__ unsigned short f2bf(float f) {
    unsigned u = __float_as_uint(f);
    unsigned r = u + 0x7FFFu + ((u >> 16) & 1u);   // RNE
    return (unsigned short)(r >> 16);
}
__device__ __forceinline__ float bf2f(unsigned short b) {
    return __uint_as_float(((unsigned)b) << 16);
}
__device__ __forceinline__ unsigned sortkey(float v) {
    unsigned u = __float_as_uint(v);
    return u ^ (0x80000000u | (unsigned)((int)u >> 31));
}
__device__ __forceinline__ float unsortf(unsigned s) {
    unsigned u = (s & 0x80000000u) ? (s ^ 0x80000000u) : ~s;
    return __uint_as_float(u);
}
__device__ __forceinline__ unsigned umin2(unsigned a, unsigned b) { return a < b ? a : b; }
__device__ __forceinline__ unsigned umax2(unsigned a, unsigned b) { return a > b ? a : b; }

// ---------------------------------------------------------------------------
// Transpose weights so GEMM lanes stream contiguous W-rows.
// ---------------------------------------------------------------------------
__global__ __launch_bounds__(256) void wtrans_kernel(
    const float* __restrict__ W1, const float* __restrict__ W2,
    const float* __restrict__ W3, const float* __restrict__ W4,
    float* __restrict__ W1t, float* __restrict__ W2t,
    float* __restrict__ W3t, float* __restrict__ W4t)
{
    const int g = blockIdx.x * 256 + threadIdx.x;
    if (g < 131072) {
        W1t[(size_t)(g & 255) * 512 + (g >> 8)] = W1[g];
    } else if (g < 262144) {
        const int i = g - 131072;
        W4t[(size_t)(i & 511) * 256 + (i >> 9)] = W4[i];
    } else if (g < 294912) {
        const int i = g - 262144;
        W2t[(size_t)(i & 127) * 256 + (i >> 7)] = W2[i];
    } else {
        const int i = g - 294912;
        W3t[(size_t)(i & 255) * 128 + (i >> 8)] = W3[i];
    }
}

// ---------------------------------------------------------------------------
// Encoder: feat -> GEMM1(reg-blocked 4x4) -> LN(in-wave) -> GELU -> LDS ->
// GEMM2(2x4) -> encoded + bf16 hi/lo split. 16 rows/block, 256 threads.
// DS:FMA = 1:16 (was 1:4). Per-output fmaf chain order unchanged (bias +
// ascending k, .x..w).
// ---------------------------------------------------------------------------
__global__ __launch_bounds__(256) void enc_kernel(
    const float* __restrict__ feat, const float* __restrict__ W1t, const float* __restrict__ b1,
    const float* __restrict__ g1, const float* __restrict__ be1,
    const float* __restrict__ W2t, const float* __restrict__ b2,
    float* __restrict__ encoded, short* __restrict__ xh, short* __restrict__ xl)
{
    __shared__ float xf[16][512];    // 32KB
    __shared__ float hb[16][256];    // 16KB
    const int tid = threadIdx.x;
    const int rbase = blockIdx.x * 16;

    {
        const float4* src = (const float4*)(feat + (size_t)rbase * 512);
        float4* dst = (float4*)&xf[0][0];
        #pragma unroll
        for (int i = 0; i < 8; ++i) dst[tid * 8 + i] = src[tid * 8 + i];
    }
    __syncthreads();

    // GEMM1: thread = (cg: 4 cols of 256, rg=wave: 4 rows of 16)
    const int cg = tid & 63, rg = tid >> 6;
    float acc[4][4];
    {
        float4 bv = *(const float4*)(b1 + cg * 4);
        #pragma unroll
        for (int r = 0; r < 4; ++r) {
            acc[r][0] = bv.x; acc[r][1] = bv.y; acc[r][2] = bv.z; acc[r][3] = bv.w;
        }
    }
    for (int k = 0; k < 512; k += 4) {
        float4 wv[4], xv[4];
        #pragma unroll
        for (int c = 0; c < 4; ++c) wv[c] = *(const float4*)(W1t + (size_t)(cg * 4 + c) * 512 + k);
        #pragma unroll
        for (int r = 0; r < 4; ++r) xv[r] = *(const float4*)&xf[rg * 4 + r][k];
        #pragma unroll
        for (int r = 0; r < 4; ++r)
            #pragma unroll
            for (int c = 0; c < 4; ++c) {
                acc[r][c] = fmaf(xv[r].x, wv[c].x, acc[r][c]);
                acc[r][c] = fmaf(xv[r].y, wv[c].y, acc[r][c]);
                acc[r][c] = fmaf(xv[r].z, wv[c].z, acc[r][c]);
                acc[r][c] = fmaf(xv[r].w, wv[c].w, acc[r][c]);
            }
    }

    // LayerNorm: row's 256 cols live in this wave -> pure shfl reduce
    float s1[4], s2[4];
    #pragma unroll
    for (int r = 0; r < 4; ++r) {
        s1[r] = acc[r][0] + acc[r][1] + acc[r][2] + acc[r][3];
        s2[r] = acc[r][0] * acc[r][0] + acc[r][1] * acc[r][1]
              + acc[r][2] * acc[r][2] + acc[r][3] * acc[r][3];
    }
    #pragma unroll
    for (int m = 1; m < 64; m <<= 1) {
        #pragma unroll
        for (int r = 0; r < 4; ++r) {
            s1[r] += __shfl_xor(s1[r], m, 64);
            s2[r] += __shfl_xor(s2[r], m, 64);
        }
    }
    {
        float4 gv = *(const float4*)(g1 + cg * 4);
        float4 bv = *(const float4*)(be1 + cg * 4);
        float gvv[4] = {gv.x, gv.y, gv.z, gv.w};
        float bvv[4] = {bv.x, bv.y, bv.z, bv.w};
        #pragma unroll
        for (int r = 0; r < 4; ++r) {
            float mu = s1[r] * (1.0f / 256.0f);
            float var = fmaxf(s2[r] * (1.0f / 256.0f) - mu * mu, 0.0f);
            float rstd = rsqrtf(var + 1e-5f);
            float h[4];
            #pragma unroll
            for (int c = 0; c < 4; ++c) {
                float t = (acc[r][c] - mu) * rstd * gvv[c] + bvv[c];
                h[c] = 0.5f * t * (1.0f + erff(t * 0.70710678118654752f));
            }
            *(float4*)&hb[rg * 4 + r][cg * 4] = make_float4(h[0], h[1], h[2], h[3]);
        }
    }
    __syncthreads();

    // GEMM2: thread = (cg2: 4 cols of 128, rg2: 2 rows of 16)
    const int cg2 = tid & 31, rg2 = tid >> 5;
    float a2[2][4];
    {
        float4 bv = *(const float4*)(b2 + cg2 * 4);
        #pragma unroll
        for (int r = 0; r < 2; ++r) {
            a2[r][0] = bv.x; a2[r][1] = bv.y; a2[r][2] = bv.z; a2[r][3] = bv.w;
        }
    }
    for (int k = 0; k < 256; k += 4) {
        float4 wv[4], hv[2];
        #pragma unroll
        for (int c = 0; c < 4; ++c) wv[c] = *(const float4*)(W2t + (size_t)(cg2 * 4 + c) * 256 + k);
        #pragma unroll
        for (int r = 0; r < 2; ++r) hv[r] = *(const float4*)&hb[rg2 * 2 + r][k];
        #pragma unroll
        for (int r = 0; r < 2; ++r)
            #pragma unroll
            for (int c = 0; c < 4; ++c) {
                a2[r][c] = fmaf(hv[r].x, wv[c].x, a2[r][c]);
                a2[r][c] = fmaf(hv[r].y, wv[c].y, a2[r][c]);
                a2[r][c] = fmaf(hv[r].z, wv[c].z, a2[r][c]);
                a2[r][c] = fmaf(hv[r].w, wv[c].w, a2[r][c]);
            }
    }
    #pragma unroll
    for (int r = 0; r < 2; ++r) {
        const size_t row = rbase + rg2 * 2 + r;
        *(float4*)(encoded + row * 128 + cg2 * 4) = make_float4(a2[r][0], a2[r][1], a2[r][2], a2[r][3]);
        short4v hh, ll;
        #pragma unroll
        for (int c = 0; c < 4; ++c) {
            unsigned short hb16 = f2bf(a2[r][c]);
            hh[c] = (short)hb16;
            ll[c] = (short)f2bf(a2[r][c] - bf2f(hb16));
        }
        *(short4v*)(xh + row * 128 + cg2 * 4) = hh;
        *(short4v*)(xl + row * 128 + cg2 * 4) = ll;
    }
}

// ---------------------------------------------------------------------------
// Split+pack codebook into bf16 MFMA-fragment-linear blobs AND cnorm.
// Blob layout per ctile (64 cols): 32KB = [hi/lo][ct4(4)][q(16)][lr(16)][8].
// ---------------------------------------------------------------------------
__global__ __launch_bounds__(256) void split_kernel(
    const float* __restrict__ cb, short* __restrict__ cpk, float* __restrict__ cnorm)
{
    const int t = threadIdx.x;
    const int col = blockIdx.x * 8 + (t >> 5);
    const int k0 = (t & 31) * 4;
    float4 v = *(const float4*)(cb + (size_t)col * 128 + k0);
    short4v h, l;
    {
        float vv[4] = {v.x, v.y, v.z, v.w};
        #pragma unroll
        for (int c = 0; c < 4; ++c) {
            unsigned short hb16 = f2bf(vv[c]);
            h[c] = (short)hb16;
            l[c] = (short)f2bf(vv[c] - bf2f(hb16));
        }
    }
    const size_t base = (size_t)(col >> 6) * 16384 + (size_t)((col >> 4) & 3) * 2048
                      + (size_t)(k0 >> 3) * 128 + (size_t)(col & 15) * 8 + (k0 & 7);
    *(short4v*)(cpk + base) = h;
    *(short4v*)(cpk + base + 8192) = l;

    float s = v.x * v.x + v.y * v.y + v.z * v.z + v.w * v.w;
    #pragma unroll
    for (int m = 1; m < 32; m <<= 1) s += __shfl_xor(s, m, 64);
    if ((t & 31) == 0) cnorm[col] = s;
}

// ---------------------------------------------------------------------------
// Pass A: bf16 MFMA distance + per-64-col-group (min, argmin, needfull).
// score = ||c||^2 - 2 x.c via 3-term bf16 split (err <~ 8e-3 incl -2x).
// Wave = 64 rows (xt=4), block = 256 rows; grid = 64 rb x 8 kq = 512.
// Epilogue per group: in-lane (v1,v2,i1) tracking (ascending col, strict <),
// packed sortable-u32 keys (idx in bits 6..1 -> min_u32 = first-index
// lexicographic; truncation ambiguity forces needfull -> safe), 2-shfl merge.
// needfull bit0 = (v2 - v1 <= EPS_G). Output gkey[group][row] u32,
// 64B-coalesced stores (kills round-5's write amplification).
// ---------------------------------------------------------------------------
__global__ __launch_bounds__(256, 2) void mfma_dist_kernel(
    const short* __restrict__ xh, const short* __restrict__ xl,
    const short* __restrict__ cpk, const float* __restrict__ cnorm,
    unsigned* __restrict__ gkey)
{
    __shared__ __align__(16) short bs[2][16384];   // 2 x 32KB
    const int tid = threadIdx.x;
    const int w = tid >> 6, l = tid & 63;
    const int lr = l & 15, lg = l >> 4;
    const int q8 = blockIdx.x & 7;
    const int rb = blockIdx.x >> 3;
    const int rbase = rb * 256 + w * 64;
    const int ctbase = q8 * 32;

    short8 xH[4][4], xL[4][4];
    #pragma unroll
    for (int xt = 0; xt < 4; ++xt) {
        const size_t rowoff = (size_t)(rbase + xt * 16 + lr) * 128;
        #pragma unroll
        for (int ks = 0; ks < 4; ++ks) {
            xH[xt][ks] = *(const short8*)(xh + rowoff + ks * 32 + lg * 8);
            xL[xt][ks] = *(const short8*)(xl + rowoff + ks * 32 + lg * 8);
        }
    }

    const char* cpkb = (const char*)cpk;
    char* lds0 = (char*)&bs[0][0];
    auto stage = [&](int buf, int ct) {
        const char* src = cpkb + ((size_t)(ctbase + ct) << 15) + (w << 13) + l * 16;
        char* dst = lds0 + (buf << 15) + (w << 13);
        #pragma unroll
        for (int i = 0; i < 8; ++i) {
            __builtin_amdgcn_global_load_lds(
                (const __attribute__((address_space(1))) unsigned int*)(src + i * 1024),
                (__attribute__((address_space(3))) unsigned int*)(dst + i * 1024),
                16, 0, 0);
        }
    };

    stage(0, 0);

    int cur = 0;
    for (int t = 0; t < 32; ++t) {
        if (t < 31) {
            stage(cur ^ 1, t + 1);
            asm volatile("s_waitcnt vmcnt(8)" ::: "memory");
        } else {
            asm volatile("s_waitcnt vmcnt(0)" ::: "memory");
        }
        __builtin_amdgcn_s_barrier();
        asm volatile("" ::: "memory");

        const short* bb = &bs[cur][0];
        f32x4 acc[4][4];   // [ct4][xt]
        #pragma unroll
        for (int c4 = 0; c4 < 4; ++c4)
            #pragma unroll
            for (int xt = 0; xt < 4; ++xt) {
                f32x4 z = {0.0f, 0.0f, 0.0f, 0.0f};
                acc[c4][xt] = z;
            }

        __builtin_amdgcn_s_setprio(1);
        #pragma unroll
        for (int ks = 0; ks < 4; ++ks) {
            short8 cH[4], cL[4];
            #pragma unroll
            for (int c4 = 0; c4 < 4; ++c4) {
                const int off = c4 * 2048 + (ks * 4 + lg) * 128 + lr * 8;
                cH[c4] = *(const short8*)(bb + off);
                cL[c4] = *(const short8*)(bb + 8192 + off);
            }
            #pragma unroll
            for (int c4 = 0; c4 < 4; ++c4)
                #pragma unroll
                for (int xt = 0; xt < 4; ++xt) {
                    acc[c4][xt] = __builtin_amdgcn_mfma_f32_16x16x32_bf16(cH[c4], xH[xt][ks], acc[c4][xt], 0, 0, 0);
                    acc[c4][xt] = __builtin_amdgcn_mfma_f32_16x16x32_bf16(cH[c4], xL[xt][ks], acc[c4][xt], 0, 0, 0);
                    acc[c4][xt] = __builtin_amdgcn_mfma_f32_16x16x32_bf16(cL[c4], xH[xt][ks], acc[c4][xt], 0, 0, 0);
                }
        }
        __builtin_amdgcn_s_setprio(0);

        // epilogue: (min, 2nd-min, argmin) over this group's 64 cols
        const int ct = ctbase + t;
        float cns[4][4];
        #pragma unroll
        for (int c4 = 0; c4 < 4; ++c4) {
            float4 cv = *(const float4*)(cnorm + ct * 64 + c4 * 16 + lg * 4);
            cns[c4][0] = cv.x; cns[c4][1] = cv.y; cns[c4][2] = cv.z; cns[c4][3] = cv.w;
        }
        const int lg4 = lg * 4;
        #pragma unroll
        for (int xt = 0; xt < 4; ++xt) {
            float v1 = 3.4e38f, v2 = 3.4e38f;
            int i1 = 0;
            #pragma unroll
            for (int c4 = 0; c4 < 4; ++c4)
                #pragma unroll
                for (int reg = 0; reg < 4; ++reg) {
                    float v = fmaf(-2.0f, acc[c4][xt][reg], cns[c4][reg]);
                    int col = c4 * 16 + lg4 + reg;           // ascending per lane
                    bool cless = v < v1;
                    v2 = fminf(v2, fmaxf(v1, v));
                    v1 = fminf(v1, v);
                    i1 = cless ? col : i1;
                }
            unsigned k1 = (sortkey(v1) & 0xFFFFFF80u) | ((unsigned)i1 << 1);
            unsigned k2 = sortkey(v2) & 0xFFFFFF80u;
            {
                unsigned o1 = (unsigned)__shfl_xor((int)k1, 16, 64);
                unsigned o2 = (unsigned)__shfl_xor((int)k2, 16, 64);
                k2 = umin2(umin2(k2, o2), umax2(k1, o1)); k1 = umin2(k1, o1);
                o1 = (unsigned)__shfl_xor((int)k1, 32, 64);
                o2 = (unsigned)__shfl_xor((int)k2, 32, 64);
                k2 = umin2(umin2(k2, o2), umax2(k1, o1)); k1 = umin2(k1, o1);
            }
            if (lg == 0) {
                float vt1 = unsortf(k1 & 0xFFFFFF80u);
                float vt2 = unsortf(k2);
                unsigned key = k1 | ((vt2 - vt1 <= EPS_G) ? 1u : 0u);
                gkey[(size_t)ct * 16384 + rbase + xt * 16 + lr] = key;
            }
        }
        asm volatile("" ::: "memory");
        __builtin_amdgcn_s_barrier();
        cur ^= 1;
    }
}

// ---------------------------------------------------------------------------
// Pass B: candidate-based exact refine. 16 rows/block. Candidates = argmin
// of qualifying groups (value <= rowmin + EPS_G); needfull groups expand to
// full 64-col exact rescan (rare). Exact fp32 wave-parallel dots;
// lexicographic (score, col) = first-index tie-break.
// ---------------------------------------------------------------------------
#define RCAP 1024
__global__ __launch_bounds__(256) void refine_kernel(
    const float* __restrict__ encoded, const float* __restrict__ cb,
    const float* __restrict__ cnorm, const unsigned* __restrict__ gkey,
    int* __restrict__ idx_ws)
{
    __shared__ unsigned rparts[4][16];
    __shared__ unsigned list[RCAP];
    __shared__ float resV[RCAP];
    __shared__ int resC[RCAP];
    __shared__ float xsm[16][128];
    __shared__ int cnt;
    const int tid = threadIdx.x;
    const int l = tid & 63, wv = tid >> 6;
    const int rbase = blockIdx.x * 16;

    if (tid == 0) cnt = 0;

    // load this group's 16 row-keys
    unsigned kk[16];
    {
        const unsigned* gp = gkey + (size_t)tid * 16384 + rbase;
        uint4 a0 = *(const uint4*)(gp + 0);
        uint4 a1 = *(const uint4*)(gp + 4);
        uint4 a2 = *(const uint4*)(gp + 8);
        uint4 a3 = *(const uint4*)(gp + 12);
        kk[0] = a0.x; kk[1] = a0.y; kk[2] = a0.z; kk[3] = a0.w;
        kk[4] = a1.x; kk[5] = a1.y; kk[6] = a1.z; kk[7] = a1.w;
        kk[8] = a2.x; kk[9] = a2.y; kk[10] = a2.z; kk[11] = a2.w;
        kk[12] = a3.x; kk[13] = a3.y; kk[14] = a3.z; kk[15] = a3.w;
    }

    // per-row min over 256 groups
    #pragma unroll
    for (int r = 0; r < 16; ++r) {
        unsigned m = kk[r];
        #pragma unroll
        for (int mk = 1; mk < 64; mk <<= 1)
            m = umin2(m, (unsigned)__shfl_xor((int)m, mk, 64));
        if (l == 0) rparts[wv][r] = m;
    }
    __syncthreads();

    float rmv[16];
    #pragma unroll
    for (int r = 0; r < 16; ++r) {
        unsigned rm = umin2(umin2(rparts[0][r], rparts[1][r]),
                            umin2(rparts[2][r], rparts[3][r]));
        rmv[r] = unsortf(rm & 0xFFFFFF80u);
    }

    // emit candidates
    #pragma unroll
    for (int r = 0; r < 16; ++r) {
        float v = unsortf(kk[r] & 0xFFFFFF80u);
        if (v <= rmv[r] + EPS_G) {
            int slot = atomicAdd(&cnt, 1);
            if (slot < RCAP)
                list[slot] = ((unsigned)r << 24) | ((kk[r] & 1u) << 23)
                           | ((unsigned)tid << 6) | ((kk[r] >> 1) & 63u);
        }
    }

    // stage encoded rows
    {
        int r = tid >> 4, i = (tid & 15) * 8;
        *(float4*)&xsm[r][i]     = *(const float4*)(encoded + (size_t)(rbase + r) * 128 + i);
        *(float4*)&xsm[r][i + 4] = *(const float4*)(encoded + (size_t)(rbase + r) * 128 + i + 4);
    }
    __syncthreads();

    const int n = min(cnt, RCAP);
    for (int i = wv; i < n; i += 4) {
        unsigned e = list[i];
        const int r = (int)(e >> 24) & 15;
        const int full = (int)(e >> 23) & 1;
        const int c0 = (int)(e & 0x3FFFu);
        const int base = full ? (c0 & ~63) : c0;
        const int ni = full ? 64 : 1;
        float bsv = 3.4e38f; int bc = 0;
        float2 xv = *(const float2*)&xsm[r][l * 2];
        for (int j = 0; j < ni; ++j) {
            const int col = base + j;
            float2 cv = *(const float2*)(cb + (size_t)col * 128 + l * 2);
            float p = fmaf(xv.y, cv.y, xv.x * cv.x);
            #pragma unroll
            for (int mk = 1; mk < 64; mk <<= 1) p += __shfl_xor(p, mk, 64);
            float sc = fmaf(-2.0f, p, cnorm[col]);
            if (sc < bsv) { bsv = sc; bc = col; }   // ascending, strict <
        }
        if (l == 0) { resV[i] = bsv; resC[i] = bc; }
    }
    __syncthreads();

    if (tid < 16) {
        float best = 3.4e38f; int bcol = KN - 1;
        for (int i = 0; i < n; ++i) {
            if ((int)((list[i] >> 24) & 15u) == tid) {
                float v = resV[i]; int c = resC[i];
                if (v < best || (v == best && c < bcol)) { best = v; bcol = c; }
            }
        }
        idx_ws[rbase + tid] = min(max(bcol, 0), KN - 1);
    }
}

// ---------------------------------------------------------------------------
// Decoder: gather -> GEMM3(4x4) -> LN(in-wave) -> GELU -> LDS -> GEMM4(8x4)
// -> per-row MSE + global sum. 16 rows/block. DS:FMA = 1:16.
// ---------------------------------------------------------------------------
__global__ __launch_bounds__(256) void dec_kernel(
    const float* __restrict__ feat, const float* __restrict__ cb,
    const float* __restrict__ W3t, const float* __restrict__ b3,
    const float* __restrict__ g2, const float* __restrict__ be2,
    const float* __restrict__ W4t, const float* __restrict__ b4,
    const int* __restrict__ idx_ws,
    float* __restrict__ re_ws, float* __restrict__ sum_ws)
{
    __shared__ float qb[16][128];    // 8KB
    __shared__ float dh[16][256];    // 16KB
    __shared__ float red[4][8];
    __shared__ int idxs[16];
    const int tid = threadIdx.x;
    const int rbase = blockIdx.x * 16;

    if (tid < 16) idxs[tid] = idx_ws[rbase + tid];
    __syncthreads();
    {
        int r = tid >> 4, i = (tid & 15) * 8;
        *(float4*)&qb[r][i]     = *(const float4*)(cb + (size_t)idxs[r] * 128 + i);
        *(float4*)&qb[r][i + 4] = *(const float4*)(cb + (size_t)idxs[r] * 128 + i + 4);
    }
    __syncthreads();

    // GEMM3: (cg: 4 cols of 256, rg=wave: 4 rows)
    const int cg = tid & 63, rg = tid >> 6;
    float acc[4][4];
    {
        float4 bv = *(const float4*)(b3 + cg * 4);
        #pragma unroll
        for (int r = 0; r < 4; ++r) {
            acc[r][0] = bv.x; acc[r][1] = bv.y; acc[r][2] = bv.z; acc[r][3] = bv.w;
        }
    }
    for (int k = 0; k < 128; k += 4) {
        float4 wv[4], qv[4];
        #pragma unroll
        for (int c = 0; c < 4; ++c) wv[c] = *(const float4*)(W3t + (size_t)(cg * 4 + c) * 128 + k);
        #pragma unroll
        for (int r = 0; r < 4; ++r) qv[r] = *(const float4*)&qb[rg * 4 + r][k];
        #pragma unroll
        for (int r = 0; r < 4; ++r)
            #pragma unroll
            for (int c = 0; c < 4; ++c) {
                acc[r][c] = fmaf(qv[r].x, wv[c].x, acc[r][c]);
                acc[r][c] = fmaf(qv[r].y, wv[c].y, acc[r][c]);
                acc[r][c] = fmaf(qv[r].z, wv[c].z, acc[r][c]);
                acc[r][c] = fmaf(qv[r].w, wv[c].w, acc[r][c]);
            }
    }

    // LayerNorm + GELU (in-wave)
    float s1[4], s2[4];
    #pragma unroll
    for (int r = 0; r < 4; ++r) {
        s1[r] = acc[r][0] + acc[r][1] + acc[r][2] + acc[r][3];
        s2[r] = acc[r][0] * acc[r][0] + acc[r][1] * acc[r][1]
              + acc[r][2] * acc[r][2] + acc[r][3] * acc[r][3];
    }
    #pragma unroll
    for (int m = 1; m < 64; m <<= 1) {
        #pragma unroll
        for (int r = 0; r < 4; ++r) {
            s1[r] += __shfl_xor(s1[r], m, 64);
            s2[r] += __shfl_xor(s2[r], m, 64);
        }
    }
    {
        float4 gv = *(const float4*)(g2 + cg * 4);
        float4 bv = *(const float4*)(be2 + cg * 4);
        float gvv[4] = {gv.x, gv.y, gv.z, gv.w};
        float bvv[4] = {bv.x, bv.y, bv.z, bv.w};
        #pragma unroll
        for (int r = 0; r < 4; ++r) {
            float mu = s1[r] * (1.0f / 256.0f);
            float var = fmaxf(s2[r] * (1.0f / 256.0f) - mu * mu, 0.0f);
            float rstd = rsqrtf(var + 1e-5f);
            float h[4];
            #pragma unroll
            for (int c = 0; c < 4; ++c) {
                float t = (acc[r][c] - mu) * rstd * gvv[c] + bvv[c];
                h[c] = 0.5f * t * (1.0f + erff(t * 0.70710678118654752f));
            }
            *(float4*)&dh[rg * 4 + r][cg * 4] = make_float4(h[0], h[1], h[2], h[3]);
        }
    }
    __syncthreads();

    // GEMM4: (cgd: 4 cols of 512, rgd: 8 rows)
    const int cgd = tid & 127, rgd = tid >> 7;
    float a4[8][4];
    {
        float4 bv = *(const float4*)(b4 + cgd * 4);
        #pragma unroll
        for (int r = 0; r < 8; ++r) {
            a4[r][0] = bv.x; a4[r][1] = bv.y; a4[r][2] = bv.z; a4[r][3] = bv.w;
        }
    }
    for (int k = 0; k < 256; k += 4) {
        float4 wv[4], hv[8];
        #pragma unroll
        for (int c = 0; c < 4; ++c) wv[c] = *(const float4*)(W4t + (size_t)(cgd * 4 + c) * 256 + k);
        #pragma unroll
        for (int r = 0; r < 8; ++r) hv[r] = *(const float4*)&dh[rgd * 8 + r][k];
        #pragma unroll
        for (int r = 0; r < 8; ++r)
            #pragma unroll
            for (int c = 0; c < 4; ++c) {
                a4[r][c] = fmaf(hv[r].x, wv[c].x, a4[r][c]);
                a4[r][c] = fmaf(hv[r].y, wv[c].y, a4[r][c]);
                a4[r][c] = fmaf(hv[r].z, wv[c].z, a4[r][c]);
                a4[r][c] = fmaf(hv[r].w, wv[c].w, a4[r][c]);
            }
    }
    // MSE
    float e[8];
    #pragma unroll
    for (int r = 0; r < 8; ++r) {
        float4 fv = *(const float4*)(feat + (size_t)(rbase + rgd * 8 + r) * 512 + cgd * 4);
        float d0 = a4[r][0] - fv.x, d1 = a4[r][1] - fv.y;
        float d2 = a4[r][2] - fv.z, d3 = a4[r][3] - fv.w;
        e[r] = d0 * d0 + d1 * d1 + d2 * d2 + d3 * d3;
    }
    #pragma unroll
    for (int m = 1; m < 64; m <<= 1) {
        #pragma unroll
        for (int r = 0; r < 8; ++r) e[r] += __shfl_xor(e[r], m, 64);
    }
    const int wave = tid >> 6, lane = tid & 63;
    if (lane == 0) {
        #pragma unroll
        for (int r = 0; r < 8; ++r) red[wave][r] = e[r];
    }
    __syncthreads();
    if (tid < 16) {
        float s = (tid < 8) ? (red[0][tid] + red[1][tid])
                            : (red[2][tid - 8] + red[3][tid - 8]);
        s *= (1.0f / 512.0f);
        re_ws[rbase + tid] = s;
        atomicAdd(sum_ws, s);
    }
}

// ---------------------------------------------------------------------------
// Finalize: scale = mean(re)+1e-8; MDL bits; write all 4 fp32 outputs.
// ---------------------------------------------------------------------------
__global__ __launch_bounds__(256) void fin_kernel(
    const float* __restrict__ re_ws, const float* __restrict__ sum_ws,
    const int* __restrict__ idx_ws, float* __restrict__ out)
{
    const int i = blockIdx.x * 256 + threadIdx.x;
    const float scale = (*sum_ws) * (1.0f / 16384.0f) + 1e-8f;
    const float re = re_ws[i];
    const float lp = -fabsf(re) / scale - logf(2.0f * scale);
    const float eb = -lp * 1.4426950408889634f;
    const float tb = 14.0f + eb;
    const float ratio = 16384.0f / tb;
    out[i]             = re;
    out[16384 + i]     = ratio;
    out[2 * 16384 + i] = tb;
    out[3 * 16384 + i] = (float)idx_ws[i];
}

// ---------------------------------------------------------------------------
extern "C" void kernel_launch(void* const* d_in, const int* in_sizes, int n_in,
                              void* d_out, int out_size, void* d_ws, size_t ws_size,
                              hipStream_t stream)
{
    const float* feat = (const float*)d_in[0];
    const float* W1   = (const float*)d_in[1];
    const float* b1   = (const float*)d_in[2];
    const float* g1   = (const float*)d_in[3];
    const float* be1  = (const float*)d_in[4];
    const float* W2   = (const float*)d_in[5];
    const float* b2   = (const float*)d_in[6];
    const float* cb   = (const float*)d_in[7];
    const float* W3   = (const float*)d_in[8];
    const float* b3   = (const float*)d_in[9];
    const float* g2   = (const float*)d_in[10];
    const float* be2  = (const float*)d_in[11];
    const float* W4   = (const float*)d_in[12];
    const float* b4   = (const float*)d_in[13];

    char* ws = (char*)d_ws;
    const size_t MB = 1u << 20;
    float*    encoded = (float*)ws;                            // 8 MB
    short*    xh      = (short*)(ws + 8 * MB);                 // 4 MB
    short*    xl      = (short*)(ws + 12 * MB);                // 4 MB
    short*    cpk     = (short*)(ws + 16 * MB);                // 8 MB
    unsigned* gkey    = (unsigned*)(ws + 24 * MB);             // 16 MB [256][16384]
    float*    W1t     = (float*)(ws + 40 * MB);                // 512 KB
    float*    W2t     = (float*)(ws + 40 * MB + (512u << 10)); // 128 KB
    float*    W3t     = (float*)(ws + 40 * MB + (640u << 10)); // 128 KB
    float*    W4t     = (float*)(ws + 40 * MB + (768u << 10)); // 512 KB
    float*    cnorm   = (float*)(ws + 41 * MB + (256u << 10)); // 64 KB
    float*    re_ws   = (float*)(ws + 41 * MB + (320u << 10)); // 64 KB
    int*      idx_ws  = (int*)(ws + 41 * MB + (384u << 10));   // 64 KB
    float*    sum_ws  = (float*)(ws + 41 * MB + (448u << 10)); // 4 B

    hipMemsetAsync(sum_ws, 0, sizeof(float), stream);

    hipLaunchKernelGGL(wtrans_kernel, dim3(1280), dim3(256), 0, stream,
                       W1, W2, W3, W4, W1t, W2t, W3t, W4t);
    hipLaunchKernelGGL(split_kernel, dim3(KN / 8), dim3(256), 0, stream, cb, cpk, cnorm);
    hipLaunchKernelGGL(enc_kernel, dim3(BN / 16), dim3(256), 0, stream,
                       feat, W1t, b1, g1, be1, W2t, b2, encoded, xh, xl);
    hipLaunchKernelGGL(mfma_dist_kernel, dim3(512), dim3(256), 0, stream,
                       xh, xl, cpk, cnorm, gkey);
    hipLaunchKernelGGL(refine_kernel, dim3(BN / 16), dim3(256), 0, stream,
                       encoded, cb, cnorm, gkey, idx_ws);
    hipLaunchKernelGGL(dec_kernel, dim3(BN / 16), dim3(256), 0, stream,
                       feat, cb, W3t, b3, g2, be2, W4t, b4,
                       idx_ws, re_ws, sum_ws);
    hipLaunchKernelGGL(fin_kernel, dim3(BN / 256), dim3(256), 0, stream,
                       re_ws, sum_ws, idx_ws, (float*)d_out);
}

// Round 8
// 505.401 us; speedup vs baseline: 2.0660x; 2.0660x over previous
//
#include <hip/hip_runtime.h>
#include <math.h>

// Problem constants (fixed by the reference)
#define BN 16384
#define DN 512
#define KN 16384
#define HN 256
#define ZN 128

#define EPS_G 0.02f   // >= 2x worst-case bf16-split score error (~8e-3)

typedef short short8 __attribute__((ext_vector_type(8)));
typedef short short4v __attribute__((ext_vector_type(4)));
typedef float f32x4 __attribute__((ext_vector_type(4)));

__device__ __forceinline__ unsigned short f2bf(float f) {
    unsigned u = __float_as_uint(f);
    unsigned r = u + 0x7FFFu + ((u >> 16) & 1u);   // RNE
    return (unsigned short)(r >> 16);
}
__device__ __forceinline__ float bf2f(unsigned short b) {
    return __uint_as_float(((unsigned)b) << 16);
}
__device__ __forceinline__ unsigned sortkey(float v) {
    unsigned u = __float_as_uint(v);
    return u ^ (0x80000000u | (unsigned)((int)u >> 31));
}
__device__ __forceinline__ float unsortf(unsigned s) {
    unsigned u = (s & 0x80000000u) ? (s ^ 0x80000000u) : ~s;
    return __uint_as_float(u);
}
__device__ __forceinline__ unsigned umin2(unsigned a, unsigned b) { return a < b ? a : b; }
__device__ __forceinline__ unsigned umax2(unsigned a, unsigned b) { return a > b ? a : b; }

// ---------------------------------------------------------------------------
// Pack weights: Wp[k][j0][c] (c = 4 col-groups in one float4) so a GEMM
// thread (lane = j0) loads ONE coalesced float4 per k supplying 4 output
// cols. Same address across waves -> L1 broadcast. Fixes round-6's 2KB-stride
// per-lane W streams (485us enc, VALUBusy 18%).
//   Wp1[(k*64+j0)*4+c]  = W1[k*256 + c*64 + j0]   (k<512)
//   Wp2[(k*32+j0)*4+c]  = W2[k*128 + c*32 + j0]   (k<256)
//   Wp3[(k*64+j0)*4+c]  = W3[k*256 + c*64 + j0]   (k<128)
//   Wp4[(k*128+j0)*4+c] = W4[k*512 + c*128 + j0]  (k<256)
// ---------------------------------------------------------------------------
__global__ __launch_bounds__(256) void wtrans_kernel(
    const float* __restrict__ W1, const float* __restrict__ W2,
    const float* __restrict__ W3, const float* __restrict__ W4,
    float* __restrict__ Wp1, float* __restrict__ Wp2,
    float* __restrict__ Wp3, float* __restrict__ Wp4)
{
    const int g = blockIdx.x * 256 + threadIdx.x;
    if (g < 131072) {
        const int k = g >> 8, j = g & 255;
        Wp1[((size_t)k * 64 + (j & 63)) * 4 + (j >> 6)] = W1[g];
    } else if (g < 262144) {
        const int i = g - 131072;
        const int k = i >> 9, d = i & 511;
        Wp4[((size_t)k * 128 + (d & 127)) * 4 + (d >> 7)] = W4[i];
    } else if (g < 294912) {
        const int i = g - 262144;
        const int k = i >> 7, j = i & 127;
        Wp2[((size_t)k * 32 + (j & 31)) * 4 + (j >> 5)] = W2[i];
    } else {
        const int i = g - 294912;
        const int k = i >> 8, j = i & 255;
        Wp3[((size_t)k * 64 + (j & 63)) * 4 + (j >> 6)] = W3[i];
    }
}

// ---------------------------------------------------------------------------
// Encoder: feat -> GEMM1(4 rows x 4 cols/thread) -> LN(in-wave) -> GELU ->
// LDS -> GEMM2(2x4) -> encoded + bf16 hi/lo split. 16 rows/block.
// Per k-quad (GEMM1): 4 coalesced W float4 + 4 ds_read_b128 + 64 FMA.
// Per-output fmaf chain: bias + ascending k (.x..w) — round-6-verified.
// ---------------------------------------------------------------------------
__global__ __launch_bounds__(256) void enc_kernel(
    const float* __restrict__ feat, const float* __restrict__ Wp1, const float* __restrict__ b1,
    const float* __restrict__ g1, const float* __restrict__ be1,
    const float* __restrict__ Wp2, const float* __restrict__ b2,
    float* __restrict__ encoded, short* __restrict__ xh, short* __restrict__ xl)
{
    __shared__ float xf[16][512];    // 32KB
    __shared__ float hb[16][256];    // 16KB
    const int tid = threadIdx.x;
    const int rbase = blockIdx.x * 16;

    {
        const float4* src = (const float4*)(feat + (size_t)rbase * 512);
        float4* dst = (float4*)&xf[0][0];
        #pragma unroll
        for (int i = 0; i < 8; ++i) dst[tid * 8 + i] = src[tid * 8 + i];
    }
    __syncthreads();

    // GEMM1: lane j0 = tid&63 -> cols {c*64+j0}; wave rg = tid>>6 -> rows rg*4..+3
    const int j0 = tid & 63, rg = tid >> 6;
    float acc[4][4];
    #pragma unroll
    for (int c = 0; c < 4; ++c) {
        float bv = b1[c * 64 + j0];
        #pragma unroll
        for (int r = 0; r < 4; ++r) acc[r][c] = bv;
    }
    for (int k = 0; k < 512; k += 4) {
        f32x4 wv[4];
        #pragma unroll
        for (int kk = 0; kk < 4; ++kk)
            wv[kk] = *(const f32x4*)(Wp1 + ((size_t)(k + kk) * 64 + j0) * 4);
        f32x4 xv[4];
        #pragma unroll
        for (int r = 0; r < 4; ++r) xv[r] = *(const f32x4*)&xf[rg * 4 + r][k];
        #pragma unroll
        for (int r = 0; r < 4; ++r)
            #pragma unroll
            for (int c = 0; c < 4; ++c) {
                acc[r][c] = fmaf(xv[r][0], wv[0][c], acc[r][c]);
                acc[r][c] = fmaf(xv[r][1], wv[1][c], acc[r][c]);
                acc[r][c] = fmaf(xv[r][2], wv[2][c], acc[r][c]);
                acc[r][c] = fmaf(xv[r][3], wv[3][c], acc[r][c]);
            }
    }

    // LayerNorm: each wave owns its 4 rows' full 256 cols -> shfl reduce
    float s1[4], s2[4];
    #pragma unroll
    for (int r = 0; r < 4; ++r) {
        s1[r] = acc[r][0] + acc[r][1] + acc[r][2] + acc[r][3];
        s2[r] = acc[r][0] * acc[r][0] + acc[r][1] * acc[r][1]
              + acc[r][2] * acc[r][2] + acc[r][3] * acc[r][3];
    }
    #pragma unroll
    for (int m = 1; m < 64; m <<= 1) {
        #pragma unroll
        for (int r = 0; r < 4; ++r) {
            s1[r] += __shfl_xor(s1[r], m, 64);
            s2[r] += __shfl_xor(s2[r], m, 64);
        }
    }
    {
        float gvv[4], bvv[4];
        #pragma unroll
        for (int c = 0; c < 4; ++c) { gvv[c] = g1[c * 64 + j0]; bvv[c] = be1[c * 64 + j0]; }
        #pragma unroll
        for (int r = 0; r < 4; ++r) {
            float mu = s1[r] * (1.0f / 256.0f);
            float var = fmaxf(s2[r] * (1.0f / 256.0f) - mu * mu, 0.0f);
            float rstd = rsqrtf(var + 1e-5f);
            #pragma unroll
            for (int c = 0; c < 4; ++c) {
                float t = (acc[r][c] - mu) * rstd * gvv[c] + bvv[c];
                hb[rg * 4 + r][c * 64 + j0] = 0.5f * t * (1.0f + erff(t * 0.70710678118654752f));
            }
        }
    }
    __syncthreads();

    // GEMM2: lane j02 = tid&31 -> cols {c*32+j02}; group rg2 = tid>>5 -> rows rg2*2..+1
    const int j02 = tid & 31, rg2 = tid >> 5;
    float a2[2][4];
    #pragma unroll
    for (int c = 0; c < 4; ++c) {
        float bv = b2[c * 32 + j02];
        #pragma unroll
        for (int r = 0; r < 2; ++r) a2[r][c] = bv;
    }
    for (int k = 0; k < 256; k += 4) {
        f32x4 wv[4];
        #pragma unroll
        for (int kk = 0; kk < 4; ++kk)
            wv[kk] = *(const f32x4*)(Wp2 + ((size_t)(k + kk) * 32 + j02) * 4);
        f32x4 hv[2];
        #pragma unroll
        for (int r = 0; r < 2; ++r) hv[r] = *(const f32x4*)&hb[rg2 * 2 + r][k];
        #pragma unroll
        for (int r = 0; r < 2; ++r)
            #pragma unroll
            for (int c = 0; c < 4; ++c) {
                a2[r][c] = fmaf(hv[r][0], wv[0][c], a2[r][c]);
                a2[r][c] = fmaf(hv[r][1], wv[1][c], a2[r][c]);
                a2[r][c] = fmaf(hv[r][2], wv[2][c], a2[r][c]);
                a2[r][c] = fmaf(hv[r][3], wv[3][c], a2[r][c]);
            }
    }
    #pragma unroll
    for (int r = 0; r < 2; ++r) {
        const size_t row = rbase + rg2 * 2 + r;
        #pragma unroll
        for (int c = 0; c < 4; ++c) {
            const size_t idx = row * 128 + c * 32 + j02;
            const float v = a2[r][c];
            encoded[idx] = v;
            unsigned short hb16 = f2bf(v);
            xh[idx] = (short)hb16;
            xl[idx] = (short)f2bf(v - bf2f(hb16));
        }
    }
}

// ---------------------------------------------------------------------------
// Split+pack codebook into bf16 MFMA-fragment-linear blobs AND cnorm.
// Blob layout per ctile (64 cols): 32KB = [hi/lo][ct4(4)][q(16)][lr(16)][8].
// ---------------------------------------------------------------------------
__global__ __launch_bounds__(256) void split_kernel(
    const float* __restrict__ cb, short* __restrict__ cpk, float* __restrict__ cnorm)
{
    const int t = threadIdx.x;
    const int col = blockIdx.x * 8 + (t >> 5);
    const int k0 = (t & 31) * 4;
    float4 v = *(const float4*)(cb + (size_t)col * 128 + k0);
    short4v h, l;
    {
        float vv[4] = {v.x, v.y, v.z, v.w};
        #pragma unroll
        for (int c = 0; c < 4; ++c) {
            unsigned short hb16 = f2bf(vv[c]);
            h[c] = (short)hb16;
            l[c] = (short)f2bf(vv[c] - bf2f(hb16));
        }
    }
    const size_t base = (size_t)(col >> 6) * 16384 + (size_t)((col >> 4) & 3) * 2048
                      + (size_t)(k0 >> 3) * 128 + (size_t)(col & 15) * 8 + (k0 & 7);
    *(short4v*)(cpk + base) = h;
    *(short4v*)(cpk + base + 8192) = l;

    float s = v.x * v.x + v.y * v.y + v.z * v.z + v.w * v.w;
    #pragma unroll
    for (int m = 1; m < 32; m <<= 1) s += __shfl_xor(s, m, 64);
    if ((t & 31) == 0) cnorm[col] = s;
}

// ---------------------------------------------------------------------------
// Pass A: bf16 MFMA distance + per-64-col-group (min, argmin, needfull).
// Unchanged from round 6 (verified): wave = 64 rows, grid 64rb x 8kq = 512;
// packed sortable-u32 keys, needfull = runner-up within EPS_G.
// ---------------------------------------------------------------------------
__global__ __launch_bounds__(256, 2) void mfma_dist_kernel(
    const short* __restrict__ xh, const short* __restrict__ xl,
    const short* __restrict__ cpk, const float* __restrict__ cnorm,
    unsigned* __restrict__ gkey)
{
    __shared__ __align__(16) short bs[2][16384];   // 2 x 32KB
    const int tid = threadIdx.x;
    const int w = tid >> 6, l = tid & 63;
    const int lr = l & 15, lg = l >> 4;
    const int q8 = blockIdx.x & 7;
    const int rb = blockIdx.x >> 3;
    const int rbase = rb * 256 + w * 64;
    const int ctbase = q8 * 32;

    short8 xH[4][4], xL[4][4];
    #pragma unroll
    for (int xt = 0; xt < 4; ++xt) {
        const size_t rowoff = (size_t)(rbase + xt * 16 + lr) * 128;
        #pragma unroll
        for (int ks = 0; ks < 4; ++ks) {
            xH[xt][ks] = *(const short8*)(xh + rowoff + ks * 32 + lg * 8);
            xL[xt][ks] = *(const short8*)(xl + rowoff + ks * 32 + lg * 8);
        }
    }

    const char* cpkb = (const char*)cpk;
    char* lds0 = (char*)&bs[0][0];
    auto stage = [&](int buf, int ct) {
        const char* src = cpkb + ((size_t)(ctbase + ct) << 15) + (w << 13) + l * 16;
        char* dst = lds0 + (buf << 15) + (w << 13);
        #pragma unroll
        for (int i = 0; i < 8; ++i) {
            __builtin_amdgcn_global_load_lds(
                (const __attribute__((address_space(1))) unsigned int*)(src + i * 1024),
                (__attribute__((address_space(3))) unsigned int*)(dst + i * 1024),
                16, 0, 0);
        }
    };

    stage(0, 0);

    int cur = 0;
    for (int t = 0; t < 32; ++t) {
        if (t < 31) {
            stage(cur ^ 1, t + 1);
            asm volatile("s_waitcnt vmcnt(8)" ::: "memory");
        } else {
            asm volatile("s_waitcnt vmcnt(0)" ::: "memory");
        }
        __builtin_amdgcn_s_barrier();
        asm volatile("" ::: "memory");

        const short* bb = &bs[cur][0];
        f32x4 acc[4][4];   // [ct4][xt]
        #pragma unroll
        for (int c4 = 0; c4 < 4; ++c4)
            #pragma unroll
            for (int xt = 0; xt < 4; ++xt) {
                f32x4 z = {0.0f, 0.0f, 0.0f, 0.0f};
                acc[c4][xt] = z;
            }

        __builtin_amdgcn_s_setprio(1);
        #pragma unroll
        for (int ks = 0; ks < 4; ++ks) {
            short8 cH[4], cL[4];
            #pragma unroll
            for (int c4 = 0; c4 < 4; ++c4) {
                const int off = c4 * 2048 + (ks * 4 + lg) * 128 + lr * 8;
                cH[c4] = *(const short8*)(bb + off);
                cL[c4] = *(const short8*)(bb + 8192 + off);
            }
            #pragma unroll
            for (int c4 = 0; c4 < 4; ++c4)
                #pragma unroll
                for (int xt = 0; xt < 4; ++xt) {
                    acc[c4][xt] = __builtin_amdgcn_mfma_f32_16x16x32_bf16(cH[c4], xH[xt][ks], acc[c4][xt], 0, 0, 0);
                    acc[c4][xt] = __builtin_amdgcn_mfma_f32_16x16x32_bf16(cH[c4], xL[xt][ks], acc[c4][xt], 0, 0, 0);
                    acc[c4][xt] = __builtin_amdgcn_mfma_f32_16x16x32_bf16(cL[c4], xH[xt][ks], acc[c4][xt], 0, 0, 0);
                }
        }
        __builtin_amdgcn_s_setprio(0);

        // epilogue: (min, 2nd-min, argmin) over this group's 64 cols
        const int ct = ctbase + t;
        float cns[4][4];
        #pragma unroll
        for (int c4 = 0; c4 < 4; ++c4) {
            float4 cv = *(const float4*)(cnorm + ct * 64 + c4 * 16 + lg * 4);
            cns[c4][0] = cv.x; cns[c4][1] = cv.y; cns[c4][2] = cv.z; cns[c4][3] = cv.w;
        }
        const int lg4 = lg * 4;
        #pragma unroll
        for (int xt = 0; xt < 4; ++xt) {
            float v1 = 3.4e38f, v2 = 3.4e38f;
            int i1 = 0;
            #pragma unroll
            for (int c4 = 0; c4 < 4; ++c4)
                #pragma unroll
                for (int reg = 0; reg < 4; ++reg) {
                    float v = fmaf(-2.0f, acc[c4][xt][reg], cns[c4][reg]);
                    int col = c4 * 16 + lg4 + reg;           // ascending per lane
                    bool cless = v < v1;
                    v2 = fminf(v2, fmaxf(v1, v));
                    v1 = fminf(v1, v);
                    i1 = cless ? col : i1;
                }
            unsigned k1 = (sortkey(v1) & 0xFFFFFF80u) | ((unsigned)i1 << 1);
            unsigned k2 = sortkey(v2) & 0xFFFFFF80u;
            {
                unsigned o1 = (unsigned)__shfl_xor((int)k1, 16, 64);
                unsigned o2 = (unsigned)__shfl_xor((int)k2, 16, 64);
                k2 = umin2(umin2(k2, o2), umax2(k1, o1)); k1 = umin2(k1, o1);
                o1 = (unsigned)__shfl_xor((int)k1, 32, 64);
                o2 = (unsigned)__shfl_xor((int)k2, 32, 64);
                k2 = umin2(umin2(k2, o2), umax2(k1, o1)); k1 = umin2(k1, o1);
            }
            if (lg == 0) {
                float vt1 = unsortf(k1 & 0xFFFFFF80u);
                float vt2 = unsortf(k2);
                unsigned key = k1 | ((vt2 - vt1 <= EPS_G) ? 1u : 0u);
                gkey[(size_t)ct * 16384 + rbase + xt * 16 + lr] = key;
            }
        }
        asm volatile("" ::: "memory");
        __builtin_amdgcn_s_barrier();
        cur ^= 1;
    }
}

// ---------------------------------------------------------------------------
// Pass B: candidate-based exact refine (unchanged from round 6, verified).
// ---------------------------------------------------------------------------
#define RCAP 1024
__global__ __launch_bounds__(256) void refine_kernel(
    const float* __restrict__ encoded, const float* __restrict__ cb,
    const float* __restrict__ cnorm, const unsigned* __restrict__ gkey,
    int* __restrict__ idx_ws)
{
    __shared__ unsigned rparts[4][16];
    __shared__ unsigned list[RCAP];
    __shared__ float resV[RCAP];
    __shared__ int resC[RCAP];
    __shared__ float xsm[16][128];
    __shared__ int cnt;
    const int tid = threadIdx.x;
    const int l = tid & 63, wv = tid >> 6;
    const int rbase = blockIdx.x * 16;

    if (tid == 0) cnt = 0;

    unsigned kk[16];
    {
        const unsigned* gp = gkey + (size_t)tid * 16384 + rbase;
        uint4 a0 = *(const uint4*)(gp + 0);
        uint4 a1 = *(const uint4*)(gp + 4);
        uint4 a2 = *(const uint4*)(gp + 8);
        uint4 a3 = *(const uint4*)(gp + 12);
        kk[0] = a0.x; kk[1] = a0.y; kk[2] = a0.z; kk[3] = a0.w;
        kk[4] = a1.x; kk[5] = a1.y; kk[6] = a1.z; kk[7] = a1.w;
        kk[8] = a2.x; kk[9] = a2.y; kk[10] = a2.z; kk[11] = a2.w;
        kk[12] = a3.x; kk[13] = a3.y; kk[14] = a3.z; kk[15] = a3.w;
    }

    #pragma unroll
    for (int r = 0; r < 16; ++r) {
        unsigned m = kk[r];
        #pragma unroll
        for (int mk = 1; mk < 64; mk <<= 1)
            m = umin2(m, (unsigned)__shfl_xor((int)m, mk, 64));
        if (l == 0) rparts[wv][r] = m;
    }
    __syncthreads();

    float rmv[16];
    #pragma unroll
    for (int r = 0; r < 16; ++r) {
        unsigned rm = umin2(umin2(rparts[0][r], rparts[1][r]),
                            umin2(rparts[2][r], rparts[3][r]));
        rmv[r] = unsortf(rm & 0xFFFFFF80u);
    }

    #pragma unroll
    for (int r = 0; r < 16; ++r) {
        float v = unsortf(kk[r] & 0xFFFFFF80u);
        if (v <= rmv[r] + EPS_G) {
            int slot = atomicAdd(&cnt, 1);
            if (slot < RCAP)
                list[slot] = ((unsigned)r << 24) | ((kk[r] & 1u) << 23)
                           | ((unsigned)tid << 6) | ((kk[r] >> 1) & 63u);
        }
    }

    {
        int r = tid >> 4, i = (tid & 15) * 8;
        *(float4*)&xsm[r][i]     = *(const float4*)(encoded + (size_t)(rbase + r) * 128 + i);
        *(float4*)&xsm[r][i + 4] = *(const float4*)(encoded + (size_t)(rbase + r) * 128 + i + 4);
    }
    __syncthreads();

    const int n = min(cnt, RCAP);
    for (int i = wv; i < n; i += 4) {
        unsigned e = list[i];
        const int r = (int)(e >> 24) & 15;
        const int full = (int)(e >> 23) & 1;
        const int c0 = (int)(e & 0x3FFFu);
        const int base = full ? (c0 & ~63) : c0;
        const int ni = full ? 64 : 1;
        float bsv = 3.4e38f; int bc = 0;
        float2 xv = *(const float2*)&xsm[r][l * 2];
        for (int j = 0; j < ni; ++j) {
            const int col = base + j;
            float2 cv = *(const float2*)(cb + (size_t)col * 128 + l * 2);
            float p = fmaf(xv.y, cv.y, xv.x * cv.x);
            #pragma unroll
            for (int mk = 1; mk < 64; mk <<= 1) p += __shfl_xor(p, mk, 64);
            float sc = fmaf(-2.0f, p, cnorm[col]);
            if (sc < bsv) { bsv = sc; bc = col; }
        }
        if (l == 0) { resV[i] = bsv; resC[i] = bc; }
    }
    __syncthreads();

    if (tid < 16) {
        float best = 3.4e38f; int bcol = KN - 1;
        for (int i = 0; i < n; ++i) {
            if ((int)((list[i] >> 24) & 15u) == tid) {
                float v = resV[i]; int c = resC[i];
                if (v < best || (v == best && c < bcol)) { best = v; bcol = c; }
            }
        }
        idx_ws[rbase + tid] = min(max(bcol, 0), KN - 1);
    }
}

// ---------------------------------------------------------------------------
// Decoder: gather -> GEMM3(4x4) -> LN(in-wave) -> GELU -> LDS -> GEMM4(8x4)
// -> per-row MSE + global sum. 16 rows/block. Packed-W coalesced loads.
// ---------------------------------------------------------------------------
__global__ __launch_bounds__(256) void dec_kernel(
    const float* __restrict__ feat, const float* __restrict__ cb,
    const float* __restrict__ Wp3, const float* __restrict__ b3,
    const float* __restrict__ g2, const float* __restrict__ be2,
    const float* __restrict__ Wp4, const float* __restrict__ b4,
    const int* __restrict__ idx_ws,
    float* __restrict__ re_ws, float* __restrict__ sum_ws)
{
    __shared__ float qb[16][128];    // 8KB
    __shared__ float dh[16][256];    // 16KB
    __shared__ float red[4][8];
    __shared__ int idxs[16];
    const int tid = threadIdx.x;
    const int rbase = blockIdx.x * 16;

    if (tid < 16) idxs[tid] = idx_ws[rbase + tid];
    __syncthreads();
    {
        int r = tid >> 4, i = (tid & 15) * 8;
        *(float4*)&qb[r][i]     = *(const float4*)(cb + (size_t)idxs[r] * 128 + i);
        *(float4*)&qb[r][i + 4] = *(const float4*)(cb + (size_t)idxs[r] * 128 + i + 4);
    }
    __syncthreads();

    // GEMM3: lane j0 = tid&63 -> cols {c*64+j0}; wave rg -> rows rg*4..+3
    const int j0 = tid & 63, rg = tid >> 6;
    float acc[4][4];
    #pragma unroll
    for (int c = 0; c < 4; ++c) {
        float bv = b3[c * 64 + j0];
        #pragma unroll
        for (int r = 0; r < 4; ++r) acc[r][c] = bv;
    }
    for (int k = 0; k < 128; k += 4) {
        f32x4 wv[4];
        #pragma unroll
        for (int kk = 0; kk < 4; ++kk)
            wv[kk] = *(const f32x4*)(Wp3 + ((size_t)(k + kk) * 64 + j0) * 4);
        f32x4 qv[4];
        #pragma unroll
        for (int r = 0; r < 4; ++r) qv[r] = *(const f32x4*)&qb[rg * 4 + r][k];
        #pragma unroll
        for (int r = 0; r < 4; ++r)
            #pragma unroll
            for (int c = 0; c < 4; ++c) {
                acc[r][c] = fmaf(qv[r][0], wv[0][c], acc[r][c]);
                acc[r][c] = fmaf(qv[r][1], wv[1][c], acc[r][c]);
                acc[r][c] = fmaf(qv[r][2], wv[2][c], acc[r][c]);
                acc[r][c] = fmaf(qv[r][3], wv[3][c], acc[r][c]);
            }
    }

    // LayerNorm + GELU (in-wave)
    float s1[4], s2[4];
    #pragma unroll
    for (int r = 0; r < 4; ++r) {
        s1[r] = acc[r][0] + acc[r][1] + acc[r][2] + acc[r][3];
        s2[r] = acc[r][0] * acc[r][0] + acc[r][1] * acc[r][1]
              + acc[r][2] * acc[r][2] + acc[r][3] * acc[r][3];
    }
    #pragma unroll
    for (int m = 1; m < 64; m <<= 1) {
        #pragma unroll
        for (int r = 0; r < 4; ++r) {
            s1[r] += __shfl_xor(s1[r], m, 64);
            s2[r] += __shfl_xor(s2[r], m, 64);
        }
    }
    {
        float gvv[4], bvv[4];
        #pragma unroll
        for (int c = 0; c < 4; ++c) { gvv[c] = g2[c * 64 + j0]; bvv[c] = be2[c * 64 + j0]; }
        #pragma unroll
        for (int r = 0; r < 4; ++r) {
            float mu = s1[r] * (1.0f / 256.0f);
            float var = fmaxf(s2[r] * (1.0f / 256.0f) - mu * mu, 0.0f);
            float rstd = rsqrtf(var + 1e-5f);
            #pragma unroll
            for (int c = 0; c < 4; ++c) {
                float t = (acc[r][c] - mu) * rstd * gvv[c] + bvv[c];
                dh[rg * 4 + r][c * 64 + j0] = 0.5f * t * (1.0f + erff(t * 0.70710678118654752f));
            }
        }
    }
    __syncthreads();

    // GEMM4: lane j04 = tid&127 -> cols {c*128+j04}; group rg4 = tid>>7 -> rows rg4*8..+7
    const int j04 = tid & 127, rg4 = tid >> 7;
    float a4[8][4];
    #pragma unroll
    for (int c = 0; c < 4; ++c) {
        float bv = b4[c * 128 + j04];
        #pragma unroll
        for (int r = 0; r < 8; ++r) a4[r][c] = bv;
    }
    for (int k = 0; k < 256; k += 4) {
        f32x4 wv[4];
        #pragma unroll
        for (int kk = 0; kk < 4; ++kk)
            wv[kk] = *(const f32x4*)(Wp4 + ((size_t)(k + kk) * 128 + j04) * 4);
        f32x4 hv[8];
        #pragma unroll
        for (int r = 0; r < 8; ++r) hv[r] = *(const f32x4*)&dh[rg4 * 8 + r][k];
        #pragma unroll
        for (int r = 0; r < 8; ++r)
            #pragma unroll
            for (int c = 0; c < 4; ++c) {
                a4[r][c] = fmaf(hv[r][0], wv[0][c], a4[r][c]);
                a4[r][c] = fmaf(hv[r][1], wv[1][c], a4[r][c]);
                a4[r][c] = fmaf(hv[r][2], wv[2][c], a4[r][c]);
                a4[r][c] = fmaf(hv[r][3], wv[3][c], a4[r][c]);
            }
    }
    // MSE: thread owns cols {c*128+j04} of rows rg4*8..+7
    float e[8];
    #pragma unroll
    for (int r = 0; r < 8; ++r) {
        const float* frow = feat + (size_t)(rbase + rg4 * 8 + r) * 512;
        float d0 = a4[r][0] - frow[j04];
        float d1 = a4[r][1] - frow[128 + j04];
        float d2 = a4[r][2] - frow[256 + j04];
        float d3 = a4[r][3] - frow[384 + j04];
        e[r] = d0 * d0 + d1 * d1 + d2 * d2 + d3 * d3;
    }
    #pragma unroll
    for (int m = 1; m < 64; m <<= 1) {
        #pragma unroll
        for (int r = 0; r < 8; ++r) e[r] += __shfl_xor(e[r], m, 64);
    }
    const int wave = tid >> 6, lane = tid & 63;
    if (lane == 0) {
        #pragma unroll
        for (int r = 0; r < 8; ++r) red[wave][r] = e[r];
    }
    __syncthreads();
    if (tid < 16) {
        float s = (tid < 8) ? (red[0][tid] + red[1][tid])
                            : (red[2][tid - 8] + red[3][tid - 8]);
        s *= (1.0f / 512.0f);
        re_ws[rbase + tid] = s;
        atomicAdd(sum_ws, s);
    }
}

// ---------------------------------------------------------------------------
// Finalize: scale = mean(re)+1e-8; MDL bits; write all 4 fp32 outputs.
// ---------------------------------------------------------------------------
__global__ __launch_bounds__(256) void fin_kernel(
    const float* __restrict__ re_ws, const float* __restrict__ sum_ws,
    const int* __restrict__ idx_ws, float* __restrict__ out)
{
    const int i = blockIdx.x * 256 + threadIdx.x;
    const float scale = (*sum_ws) * (1.0f / 16384.0f) + 1e-8f;
    const float re = re_ws[i];
    const float lp = -fabsf(re) / scale - logf(2.0f * scale);
    const float eb = -lp * 1.4426950408889634f;
    const float tb = 14.0f + eb;
    const float ratio = 16384.0f / tb;
    out[i]             = re;
    out[16384 + i]     = ratio;
    out[2 * 16384 + i] = tb;
    out[3 * 16384 + i] = (float)idx_ws[i];
}

// ---------------------------------------------------------------------------
extern "C" void kernel_launch(void* const* d_in, const int* in_sizes, int n_in,
                              void* d_out, int out_size, void* d_ws, size_t ws_size,
                              hipStream_t stream)
{
    const float* feat = (const float*)d_in[0];
    const float* W1   = (const float*)d_in[1];
    const float* b1   = (const float*)d_in[2];
    const float* g1   = (const float*)d_in[3];
    const float* be1  = (const float*)d_in[4];
    const float* W2   = (const float*)d_in[5];
    const float* b2   = (const float*)d_in[6];
    const float* cb   = (const float*)d_in[7];
    const float* W3   = (const float*)d_in[8];
    const float* b3   = (const float*)d_in[9];
    const float* g2   = (const float*)d_in[10];
    const float* be2  = (const float*)d_in[11];
    const float* W4   = (const float*)d_in[12];
    const float* b4   = (const float*)d_in[13];

    char* ws = (char*)d_ws;
    const size_t MB = 1u << 20;
    float*    encoded = (float*)ws;                            // 8 MB
    short*    xh      = (short*)(ws + 8 * MB);                 // 4 MB
    short*    xl      = (short*)(ws + 12 * MB);                // 4 MB
    short*    cpk     = (short*)(ws + 16 * MB);                // 8 MB
    unsigned* gkey    = (unsigned*)(ws + 24 * MB);             // 16 MB [256][16384]
    float*    Wp1     = (float*)(ws + 40 * MB);                // 512 KB
    float*    Wp2     = (float*)(ws + 40 * MB + (512u << 10)); // 128 KB
    float*    Wp3     = (float*)(ws + 40 * MB + (640u << 10)); // 128 KB
    float*    Wp4     = (float*)(ws + 40 * MB + (768u << 10)); // 512 KB
    float*    cnorm   = (float*)(ws + 41 * MB + (256u << 10)); // 64 KB
    float*    re_ws   = (float*)(ws + 41 * MB + (320u << 10)); // 64 KB
    int*      idx_ws  = (int*)(ws + 41 * MB + (384u << 10));   // 64 KB
    float*    sum_ws  = (float*)(ws + 41 * MB + (448u << 10)); // 4 B

    hipMemsetAsync(sum_ws, 0, sizeof(float), stream);

    hipLaunchKernelGGL(wtrans_kernel, dim3(1280), dim3(256), 0, stream,
                       W1, W2, W3, W4, Wp1, Wp2, Wp3, Wp4);
    hipLaunchKernelGGL(split_kernel, dim3(KN / 8), dim3(256), 0, stream, cb, cpk, cnorm);
    hipLaunchKernelGGL(enc_kernel, dim3(BN / 16), dim3(256), 0, stream,
                       feat, Wp1, b1, g1, be1, Wp2, b2, encoded, xh, xl);
    hipLaunchKernelGGL(mfma_dist_kernel, dim3(512), dim3(256), 0, stream,
                       xh, xl, cpk, cnorm, gkey);
    hipLaunchKernelGGL(refine_kernel, dim3(BN / 16), dim3(256), 0, stream,
                       encoded, cb, cnorm, gkey, idx_ws);
    hipLaunchKernelGGL(dec_kernel, dim3(BN / 16), dim3(256), 0, stream,
                       feat, cb, Wp3, b3, g2, be2, Wp4, b4,
                       idx_ws, re_ws, sum_ws);
    hipLaunchKernelGGL(fin_kernel, dim3(BN / 256), dim3(256), 0, stream,
                       re_ws, sum_ws, idx_ws, (float*)d_out);
}

// Round 10
// 482.649 us; speedup vs baseline: 2.1634x; 1.0471x over previous
//
#include <hip/hip_runtime.h>
#include <math.h>

// Problem constants (fixed by the reference)
#define BN 16384
#define DN 512
#define KN 16384
#define HN 256
#define ZN 128

// 2-term f16 split: score error <= ~2^-11 * Sum|x||c| (~0.008 worst).
// EPS_G must be >= 2x that bound; 0.04 gives >=2.5x margin.
#define EPS_G 0.04f

typedef _Float16 f16x8 __attribute__((ext_vector_type(8)));
typedef _Float16 f16x4 __attribute__((ext_vector_type(4)));
typedef float f32x4 __attribute__((ext_vector_type(4)));

__device__ __forceinline__ unsigned sortkey(float v) {
    unsigned u = __float_as_uint(v);
    return u ^ (0x80000000u | (unsigned)((int)u >> 31));
}
__device__ __forceinline__ float unsortf(unsigned s) {
    unsigned u = (s & 0x80000000u) ? (s ^ 0x80000000u) : ~s;
    return __uint_as_float(u);
}
__device__ __forceinline__ unsigned umin2(unsigned a, unsigned b) { return a < b ? a : b; }
__device__ __forceinline__ unsigned umax2(unsigned a, unsigned b) { return a > b ? a : b; }

// ---------------------------------------------------------------------------
// Pack weights: Wp[k][j0][c] (c = 4 col-groups in one float4) so a GEMM
// thread (lane = j0) loads ONE coalesced float4 per k supplying 4 output
// cols. Same address across waves -> L1 broadcast.
// ---------------------------------------------------------------------------
__global__ __launch_bounds__(256) void wtrans_kernel(
    const float* __restrict__ W1, const float* __restrict__ W2,
    const float* __restrict__ W3, const float* __restrict__ W4,
    float* __restrict__ Wp1, float* __restrict__ Wp2,
    float* __restrict__ Wp3, float* __restrict__ Wp4)
{
    const int g = blockIdx.x * 256 + threadIdx.x;
    if (g < 131072) {
        const int k = g >> 8, j = g & 255;
        Wp1[((size_t)k * 64 + (j & 63)) * 4 + (j >> 6)] = W1[g];
    } else if (g < 262144) {
        const int i = g - 131072;
        const int k = i >> 9, d = i & 511;
        Wp4[((size_t)k * 128 + (d & 127)) * 4 + (d >> 7)] = W4[i];
    } else if (g < 294912) {
        const int i = g - 262144;
        const int k = i >> 7, j = i & 127;
        Wp2[((size_t)k * 32 + (j & 31)) * 4 + (j >> 5)] = W2[i];
    } else {
        const int i = g - 294912;
        const int k = i >> 8, j = i & 255;
        Wp3[((size_t)k * 64 + (j & 63)) * 4 + (j >> 6)] = W3[i];
    }
}

// ---------------------------------------------------------------------------
// Encoder: feat -> GEMM1(4 rows x 4 cols/thread) -> LN(in-wave) -> GELU ->
// LDS -> GEMM2(2x4) -> encoded + f16 hi/lo split. 16 rows/block.
// (round-8-verified structure; only the split dtype changed bf16->f16)
// ---------------------------------------------------------------------------
__global__ __launch_bounds__(256) void enc_kernel(
    const float* __restrict__ feat, const float* __restrict__ Wp1, const float* __restrict__ b1,
    const float* __restrict__ g1, const float* __restrict__ be1,
    const float* __restrict__ Wp2, const float* __restrict__ b2,
    float* __restrict__ encoded, _Float16* __restrict__ xh, _Float16* __restrict__ xl)
{
    __shared__ float xf[16][512];    // 32KB
    __shared__ float hb[16][256];    // 16KB
    const int tid = threadIdx.x;
    const int rbase = blockIdx.x * 16;

    {
        const float4* src = (const float4*)(feat + (size_t)rbase * 512);
        float4* dst = (float4*)&xf[0][0];
        #pragma unroll
        for (int i = 0; i < 8; ++i) dst[tid * 8 + i] = src[tid * 8 + i];
    }
    __syncthreads();

    // GEMM1: lane j0 = tid&63 -> cols {c*64+j0}; wave rg = tid>>6 -> rows rg*4..+3
    const int j0 = tid & 63, rg = tid >> 6;
    float acc[4][4];
    #pragma unroll
    for (int c = 0; c < 4; ++c) {
        float bv = b1[c * 64 + j0];
        #pragma unroll
        for (int r = 0; r < 4; ++r) acc[r][c] = bv;
    }
    for (int k = 0; k < 512; k += 4) {
        f32x4 wv[4];
        #pragma unroll
        for (int kk = 0; kk < 4; ++kk)
            wv[kk] = *(const f32x4*)(Wp1 + ((size_t)(k + kk) * 64 + j0) * 4);
        f32x4 xv[4];
        #pragma unroll
        for (int r = 0; r < 4; ++r) xv[r] = *(const f32x4*)&xf[rg * 4 + r][k];
        #pragma unroll
        for (int r = 0; r < 4; ++r)
            #pragma unroll
            for (int c = 0; c < 4; ++c) {
                acc[r][c] = fmaf(xv[r][0], wv[0][c], acc[r][c]);
                acc[r][c] = fmaf(xv[r][1], wv[1][c], acc[r][c]);
                acc[r][c] = fmaf(xv[r][2], wv[2][c], acc[r][c]);
                acc[r][c] = fmaf(xv[r][3], wv[3][c], acc[r][c]);
            }
    }

    // LayerNorm: each wave owns its 4 rows' full 256 cols -> shfl reduce
    float s1[4], s2[4];
    #pragma unroll
    for (int r = 0; r < 4; ++r) {
        s1[r] = acc[r][0] + acc[r][1] + acc[r][2] + acc[r][3];
        s2[r] = acc[r][0] * acc[r][0] + acc[r][1] * acc[r][1]
              + acc[r][2] * acc[r][2] + acc[r][3] * acc[r][3];
    }
    #pragma unroll
    for (int m = 1; m < 64; m <<= 1) {
        #pragma unroll
        for (int r = 0; r < 4; ++r) {
            s1[r] += __shfl_xor(s1[r], m, 64);
            s2[r] += __shfl_xor(s2[r], m, 64);
        }
    }
    {
        float gvv[4], bvv[4];
        #pragma unroll
        for (int c = 0; c < 4; ++c) { gvv[c] = g1[c * 64 + j0]; bvv[c] = be1[c * 64 + j0]; }
        #pragma unroll
        for (int r = 0; r < 4; ++r) {
            float mu = s1[r] * (1.0f / 256.0f);
            float var = fmaxf(s2[r] * (1.0f / 256.0f) - mu * mu, 0.0f);
            float rstd = rsqrtf(var + 1e-5f);
            #pragma unroll
            for (int c = 0; c < 4; ++c) {
                float t = (acc[r][c] - mu) * rstd * gvv[c] + bvv[c];
                hb[rg * 4 + r][c * 64 + j0] = 0.5f * t * (1.0f + erff(t * 0.70710678118654752f));
            }
        }
    }
    __syncthreads();

    // GEMM2: lane j02 = tid&31 -> cols {c*32+j02}; group rg2 = tid>>5 -> rows rg2*2..+1
    const int j02 = tid & 31, rg2 = tid >> 5;
    float a2[2][4];
    #pragma unroll
    for (int c = 0; c < 4; ++c) {
        float bv = b2[c * 32 + j02];
        #pragma unroll
        for (int r = 0; r < 2; ++r) a2[r][c] = bv;
    }
    for (int k = 0; k < 256; k += 4) {
        f32x4 wv[4];
        #pragma unroll
        for (int kk = 0; kk < 4; ++kk)
            wv[kk] = *(const f32x4*)(Wp2 + ((size_t)(k + kk) * 32 + j02) * 4);
        f32x4 hv[2];
        #pragma unroll
        for (int r = 0; r < 2; ++r) hv[r] = *(const f32x4*)&hb[rg2 * 2 + r][k];
        #pragma unroll
        for (int r = 0; r < 2; ++r)
            #pragma unroll
            for (int c = 0; c < 4; ++c) {
                a2[r][c] = fmaf(hv[r][0], wv[0][c], a2[r][c]);
                a2[r][c] = fmaf(hv[r][1], wv[1][c], a2[r][c]);
                a2[r][c] = fmaf(hv[r][2], wv[2][c], a2[r][c]);
                a2[r][c] = fmaf(hv[r][3], wv[3][c], a2[r][c]);
            }
    }
    #pragma unroll
    for (int r = 0; r < 2; ++r) {
        const size_t row = rbase + rg2 * 2 + r;
        #pragma unroll
        for (int c = 0; c < 4; ++c) {
            const size_t idx = row * 128 + c * 32 + j02;
            const float v = a2[r][c];
            encoded[idx] = v;
            _Float16 hh = (_Float16)v;
            xh[idx] = hh;
            xl[idx] = (_Float16)(v - (float)hh);
        }
    }
}

// ---------------------------------------------------------------------------
// Split codebook into f16-hi MFMA-fragment-linear blobs AND cnorm.
// Blob layout per ctile (64 cols): 16KB = [ct4(4)][q(16)][lr(16)][8] f16.
// (2-term split: only the hi half is staged; x carries hi+lo.)
// ---------------------------------------------------------------------------
__global__ __launch_bounds__(256) void split_kernel(
    const float* __restrict__ cb, _Float16* __restrict__ cpk, float* __restrict__ cnorm)
{
    const int t = threadIdx.x;
    const int col = blockIdx.x * 8 + (t >> 5);
    const int k0 = (t & 31) * 4;
    float4 v = *(const float4*)(cb + (size_t)col * 128 + k0);
    f16x4 h;
    h.x = (_Float16)v.x;
    h.y = (_Float16)v.y;
    h.z = (_Float16)v.z;
    h.w = (_Float16)v.w;
    const size_t base = (size_t)(col >> 6) * 8192 + (size_t)((col >> 4) & 3) * 2048
                      + (size_t)(k0 >> 3) * 128 + (size_t)(col & 15) * 8 + (k0 & 7);
    *(f16x4*)(cpk + base) = h;

    float s = v.x * v.x + v.y * v.y + v.z * v.z + v.w * v.w;
    #pragma unroll
    for (int m = 1; m < 32; m <<= 1) s += __shfl_xor(s, m, 64);
    if ((t & 31) == 0) cnorm[col] = s;
}

// ---------------------------------------------------------------------------
// Pass A: f16 2-term MFMA distance + per-64-col-group (min, argmin, needfull).
// score = ||c||^2 - 2 x.ch via xh.ch + xl.ch (= x.ch exactly; err = x.(c-ch)
// <= ~2^-11 Sum|x||c| ~ 0.008 worst; EPS_G = 0.04 >= 2.5x margin).
// DS traffic halved vs round 8 (16KB blob: cH only, 16 ds_read/wave/step).
// Wave = 64 rows (xt=4), grid 64rb x 8kq = 512. vmcnt(4) counted prefetch.
// ---------------------------------------------------------------------------
__global__ __launch_bounds__(256, 2) void mfma_dist_kernel(
    const _Float16* __restrict__ xh, const _Float16* __restrict__ xl,
    const _Float16* __restrict__ cpk, const float* __restrict__ cnorm,
    unsigned* __restrict__ gkey)
{
    __shared__ __align__(16) _Float16 bs[2][8192];   // 2 x 16KB
    const int tid = threadIdx.x;
    const int w = tid >> 6, l = tid & 63;
    const int lr = l & 15, lg = l >> 4;
    const int q8 = blockIdx.x & 7;
    const int rb = blockIdx.x >> 3;
    const int rbase = rb * 256 + w * 64;
    const int ctbase = q8 * 32;

    f16x8 xH[4][4], xL[4][4];
    #pragma unroll
    for (int xt = 0; xt < 4; ++xt) {
        const size_t rowoff = (size_t)(rbase + xt * 16 + lr) * 128;
        #pragma unroll
        for (int ks = 0; ks < 4; ++ks) {
            xH[xt][ks] = *(const f16x8*)(xh + rowoff + ks * 32 + lg * 8);
            xL[xt][ks] = *(const f16x8*)(xl + rowoff + ks * 32 + lg * 8);
        }
    }

    const char* cpkb = (const char*)cpk;
    char* lds0 = (char*)&bs[0][0];
    auto stage = [&](int buf, int ct) {
        const char* src = cpkb + ((size_t)(ctbase + ct) << 14) + (w << 12) + l * 16;
        char* dst = lds0 + (buf << 14) + (w << 12);
        #pragma unroll
        for (int i = 0; i < 4; ++i) {
            __builtin_amdgcn_global_load_lds(
                (const __attribute__((address_space(1))) unsigned int*)(src + i * 1024),
                (__attribute__((address_space(3))) unsigned int*)(dst + i * 1024),
                16, 0, 0);
        }
    };

    stage(0, 0);

    int cur = 0;
    for (int t = 0; t < 32; ++t) {
        if (t < 31) {
            stage(cur ^ 1, t + 1);
            asm volatile("s_waitcnt vmcnt(4)" ::: "memory");  // drain cur, keep next in flight
        } else {
            asm volatile("s_waitcnt vmcnt(0)" ::: "memory");
        }
        __builtin_amdgcn_s_barrier();
        asm volatile("" ::: "memory");

        const _Float16* bb = &bs[cur][0];
        f32x4 acc[4][4];   // [ct4][xt]
        #pragma unroll
        for (int c4 = 0; c4 < 4; ++c4)
            #pragma unroll
            for (int xt = 0; xt < 4; ++xt) {
                f32x4 z = {0.0f, 0.0f, 0.0f, 0.0f};
                acc[c4][xt] = z;
            }

        __builtin_amdgcn_s_setprio(1);
        #pragma unroll
        for (int ks = 0; ks < 4; ++ks) {
            f16x8 cH[4];
            #pragma unroll
            for (int c4 = 0; c4 < 4; ++c4) {
                const int off = c4 * 2048 + (ks * 4 + lg) * 128 + lr * 8;
                cH[c4] = *(const f16x8*)(bb + off);
            }
            #pragma unroll
            for (int c4 = 0; c4 < 4; ++c4)
                #pragma unroll
                for (int xt = 0; xt < 4; ++xt) {
                    acc[c4][xt] = __builtin_amdgcn_mfma_f32_16x16x32_f16(cH[c4], xH[xt][ks], acc[c4][xt], 0, 0, 0);
                    acc[c4][xt] = __builtin_amdgcn_mfma_f32_16x16x32_f16(cH[c4], xL[xt][ks], acc[c4][xt], 0, 0, 0);
                }
        }
        __builtin_amdgcn_s_setprio(0);

        // epilogue: (min, 2nd-min, argmin) over this group's 64 cols
        const int ct = ctbase + t;
        float cns[4][4];
        #pragma unroll
        for (int c4 = 0; c4 < 4; ++c4) {
            float4 cv = *(const float4*)(cnorm + ct * 64 + c4 * 16 + lg * 4);
            cns[c4][0] = cv.x; cns[c4][1] = cv.y; cns[c4][2] = cv.z; cns[c4][3] = cv.w;
        }
        const int lg4 = lg * 4;
        #pragma unroll
        for (int xt = 0; xt < 4; ++xt) {
            float v1 = 3.4e38f, v2 = 3.4e38f;
            int i1 = 0;
            #pragma unroll
            for (int c4 = 0; c4 < 4; ++c4)
                #pragma unroll
                for (int reg = 0; reg < 4; ++reg) {
                    float v = fmaf(-2.0f, acc[c4][xt][reg], cns[c4][reg]);
                    int col = c4 * 16 + lg4 + reg;           // ascending per lane
                    bool cless = v < v1;
                    v2 = fminf(v2, fmaxf(v1, v));
                    v1 = fminf(v1, v);
                    i1 = cless ? col : i1;
                }
            unsigned k1 = (sortkey(v1) & 0xFFFFFF80u) | ((unsigned)i1 << 1);
            unsigned k2 = sortkey(v2) & 0xFFFFFF80u;
            {
                unsigned o1 = (unsigned)__shfl_xor((int)k1, 16, 64);
                unsigned o2 = (unsigned)__shfl_xor((int)k2, 16, 64);
                k2 = umin2(umin2(k2, o2), umax2(k1, o1)); k1 = umin2(k1, o1);
                o1 = (unsigned)__shfl_xor((int)k1, 32, 64);
                o2 = (unsigned)__shfl_xor((int)k2, 32, 64);
                k2 = umin2(umin2(k2, o2), umax2(k1, o1)); k1 = umin2(k1, o1);
            }
            if (lg == 0) {
                float vt1 = unsortf(k1 & 0xFFFFFF80u);
                float vt2 = unsortf(k2);
                unsigned key = k1 | ((vt2 - vt1 <= EPS_G) ? 1u : 0u);
                gkey[(size_t)ct * 16384 + rbase + xt * 16 + lr] = key;
            }
        }
        asm volatile("" ::: "memory");
        __builtin_amdgcn_s_barrier();
        cur ^= 1;
    }
}

// ---------------------------------------------------------------------------
// Pass B: candidate-based exact refine (round-8-verified; EPS via macro).
// ---------------------------------------------------------------------------
#define RCAP 1024
__global__ __launch_bounds__(256) void refine_kernel(
    const float* __restrict__ encoded, const float* __restrict__ cb,
    const float* __restrict__ cnorm, const unsigned* __restrict__ gkey,
    int* __restrict__ idx_ws)
{
    __shared__ unsigned rparts[4][16];
    __shared__ unsigned list[RCAP];
    __shared__ float resV[RCAP];
    __shared__ int resC[RCAP];
    __shared__ float xsm[16][128];
    __shared__ int cnt;
    const int tid = threadIdx.x;
    const int l = tid & 63, wv = tid >> 6;
    const int rbase = blockIdx.x * 16;

    if (tid == 0) cnt = 0;

    unsigned kk[16];
    {
        const unsigned* gp = gkey + (size_t)tid * 16384 + rbase;
        uint4 a0 = *(const uint4*)(gp + 0);
        uint4 a1 = *(const uint4*)(gp + 4);
        uint4 a2 = *(const uint4*)(gp + 8);
        uint4 a3 = *(const uint4*)(gp + 12);
        kk[0] = a0.x; kk[1] = a0.y; kk[2] = a0.z; kk[3] = a0.w;
        kk[4] = a1.x; kk[5] = a1.y; kk[6] = a1.z; kk[7] = a1.w;
        kk[8] = a2.x; kk[9] = a2.y; kk[10] = a2.z; kk[11] = a2.w;
        kk[12] = a3.x; kk[13] = a3.y; kk[14] = a3.z; kk[15] = a3.w;
    }

    #pragma unroll
    for (int r = 0; r < 16; ++r) {
        unsigned m = kk[r];
        #pragma unroll
        for (int mk = 1; mk < 64; mk <<= 1)
            m = umin2(m, (unsigned)__shfl_xor((int)m, mk, 64));
        if (l == 0) rparts[wv][r] = m;
    }
    __syncthreads();

    float rmv[16];
    #pragma unroll
    for (int r = 0; r < 16; ++r) {
        unsigned rm = umin2(umin2(rparts[0][r], rparts[1][r]),
                            umin2(rparts[2][r], rparts[3][r]));
        rmv[r] = unsortf(rm & 0xFFFFFF80u);
    }

    #pragma unroll
    for (int r = 0; r < 16; ++r) {
        float v = unsortf(kk[r] & 0xFFFFFF80u);
        if (v <= rmv[r] + EPS_G) {
            int slot = atomicAdd(&cnt, 1);
            if (slot < RCAP)
                list[slot] = ((unsigned)r << 24) | ((kk[r] & 1u) << 23)
                           | ((unsigned)tid << 6) | ((kk[r] >> 1) & 63u);
        }
    }

    {
        int r = tid >> 4, i = (tid & 15) * 8;
        *(float4*)&xsm[r][i]     = *(const float4*)(encoded + (size_t)(rbase + r) * 128 + i);
        *(float4*)&xsm[r][i + 4] = *(const float4*)(encoded + (size_t)(rbase + r) * 128 + i + 4);
    }
    __syncthreads();

    const int n = min(cnt, RCAP);
    for (int i = wv; i < n; i += 4) {
        unsigned e = list[i];
        const int r = (int)(e >> 24) & 15;
        const int full = (int)(e >> 23) & 1;
        const int c0 = (int)(e & 0x3FFFu);
        const int base = full ? (c0 & ~63) : c0;
        const int ni = full ? 64 : 1;
        float bsv = 3.4e38f; int bc = 0;
        float2 xv = *(const float2*)&xsm[r][l * 2];
        for (int j = 0; j < ni; ++j) {
            const int col = base + j;
            float2 cv = *(const float2*)(cb + (size_t)col * 128 + l * 2);
            float p = fmaf(xv.y, cv.y, xv.x * cv.x);
            #pragma unroll
            for (int mk = 1; mk < 64; mk <<= 1) p += __shfl_xor(p, mk, 64);
            float sc = fmaf(-2.0f, p, cnorm[col]);
            if (sc < bsv) { bsv = sc; bc = col; }
        }
        if (l == 0) { resV[i] = bsv; resC[i] = bc; }
    }
    __syncthreads();

    if (tid < 16) {
        float best = 3.4e38f; int bcol = KN - 1;
        for (int i = 0; i < n; ++i) {
            if ((int)((list[i] >> 24) & 15u) == tid) {
                float v = resV[i]; int c = resC[i];
                if (v < best || (v == best && c < bcol)) { best = v; bcol = c; }
            }
        }
        idx_ws[rbase + tid] = min(max(bcol, 0), KN - 1);
    }
}

// ---------------------------------------------------------------------------
// Decoder: gather -> GEMM3(4x4) -> LN(in-wave) -> GELU -> LDS -> GEMM4(8x4)
// -> per-row MSE + global sum. 16 rows/block. (round-8-verified)
// ---------------------------------------------------------------------------
__global__ __launch_bounds__(256) void dec_kernel(
    const float* __restrict__ feat, const float* __restrict__ cb,
    const float* __restrict__ Wp3, const float* __restrict__ b3,
    const float* __restrict__ g2, const float* __restrict__ be2,
    const float* __restrict__ Wp4, const float* __restrict__ b4,
    const int* __restrict__ idx_ws,
    float* __restrict__ re_ws, float* __restrict__ sum_ws)
{
    __shared__ float qb[16][128];    // 8KB
    __shared__ float dh[16][256];    // 16KB
    __shared__ float red[4][8];
    __shared__ int idxs[16];
    const int tid = threadIdx.x;
    const int rbase = blockIdx.x * 16;

    if (tid < 16) idxs[tid] = idx_ws[rbase + tid];
    __syncthreads();
    {
        int r = tid >> 4, i = (tid & 15) * 8;
        *(float4*)&qb[r][i]     = *(const float4*)(cb + (size_t)idxs[r] * 128 + i);
        *(float4*)&qb[r][i + 4] = *(const float4*)(cb + (size_t)idxs[r] * 128 + i + 4);
    }
    __syncthreads();

    // GEMM3: lane j0 = tid&63 -> cols {c*64+j0}; wave rg -> rows rg*4..+3
    const int j0 = tid & 63, rg = tid >> 6;
    float acc[4][4];
    #pragma unroll
    for (int c = 0; c < 4; ++c) {
        float bv = b3[c * 64 + j0];
        #pragma unroll
        for (int r = 0; r < 4; ++r) acc[r][c] = bv;
    }
    for (int k = 0; k < 128; k += 4) {
        f32x4 wv[4];
        #pragma unroll
        for (int kk = 0; kk < 4; ++kk)
            wv[kk] = *(const f32x4*)(Wp3 + ((size_t)(k + kk) * 64 + j0) * 4);
        f32x4 qv[4];
        #pragma unroll
        for (int r = 0; r < 4; ++r) qv[r] = *(const f32x4*)&qb[rg * 4 + r][k];
        #pragma unroll
        for (int r = 0; r < 4; ++r)
            #pragma unroll
            for (int c = 0; c < 4; ++c) {
                acc[r][c] = fmaf(qv[r][0], wv[0][c], acc[r][c]);
                acc[r][c] = fmaf(qv[r][1], wv[1][c], acc[r][c]);
                acc[r][c] = fmaf(qv[r][2], wv[2][c], acc[r][c]);
                acc[r][c] = fmaf(qv[r][3], wv[3][c], acc[r][c]);
            }
    }

    // LayerNorm + GELU (in-wave)
    float s1[4], s2[4];
    #pragma unroll
    for (int r = 0; r < 4; ++r) {
        s1[r] = acc[r][0] + acc[r][1] + acc[r][2] + acc[r][3];
        s2[r] = acc[r][0] * acc[r][0] + acc[r][1] * acc[r][1]
              + acc[r][2] * acc[r][2] + acc[r][3] * acc[r][3];
    }
    #pragma unroll
    for (int m = 1; m < 64; m <<= 1) {
        #pragma unroll
        for (int r = 0; r < 4; ++r) {
            s1[r] += __shfl_xor(s1[r], m, 64);
            s2[r] += __shfl_xor(s2[r], m, 64);
        }
    }
    {
        float gvv[4], bvv[4];
        #pragma unroll
        for (int c = 0; c < 4; ++c) { gvv[c] = g2[c * 64 + j0]; bvv[c] = be2[c * 64 + j0]; }
        #pragma unroll
        for (int r = 0; r < 4; ++r) {
            float mu = s1[r] * (1.0f / 256.0f);
            float var = fmaxf(s2[r] * (1.0f / 256.0f) - mu * mu, 0.0f);
            float rstd = rsqrtf(var + 1e-5f);
            #pragma unroll
            for (int c = 0; c < 4; ++c) {
                float t = (acc[r][c] - mu) * rstd * gvv[c] + bvv[c];
                dh[rg * 4 + r][c * 64 + j0] = 0.5f * t * (1.0f + erff(t * 0.70710678118654752f));
            }
        }
    }
    __syncthreads();

    // GEMM4: lane j04 = tid&127 -> cols {c*128+j04}; group rg4 = tid>>7 -> rows rg4*8..+7
    const int j04 = tid & 127, rg4 = tid >> 7;
    float a4[8][4];
    #pragma unroll
    for (int c = 0; c < 4; ++c) {
        float bv = b4[c * 128 + j04];
        #pragma unroll
        for (int r = 0; r < 8; ++r) a4[r][c] = bv;
    }
    for (int k = 0; k < 256; k += 4) {
        f32x4 wv[4];
        #pragma unroll
        for (int kk = 0; kk < 4; ++kk)
            wv[kk] = *(const f32x4*)(Wp4 + ((size_t)(k + kk) * 128 + j04) * 4);
        f32x4 hv[8];
        #pragma unroll
        for (int r = 0; r < 8; ++r) hv[r] = *(const f32x4*)&dh[rg4 * 8 + r][k];
        #pragma unroll
        for (int r = 0; r < 8; ++r)
            #pragma unroll
            for (int c = 0; c < 4; ++c) {
                a4[r][c] = fmaf(hv[r][0], wv[0][c], a4[r][c]);
                a4[r][c] = fmaf(hv[r][1], wv[1][c], a4[r][c]);
                a4[r][c] = fmaf(hv[r][2], wv[2][c], a4[r][c]);
                a4[r][c] = fmaf(hv[r][3], wv[3][c], a4[r][c]);
            }
    }
    // MSE: thread owns cols {c*128+j04} of rows rg4*8..+7
    float e[8];
    #pragma unroll
    for (int r = 0; r < 8; ++r) {
        const float* frow = feat + (size_t)(rbase + rg4 * 8 + r) * 512;
        float d0 = a4[r][0] - frow[j04];
        float d1 = a4[r][1] - frow[128 + j04];
        float d2 = a4[r][2] - frow[256 + j04];
        float d3 = a4[r][3] - frow[384 + j04];
        e[r] = d0 * d0 + d1 * d1 + d2 * d2 + d3 * d3;
    }
    #pragma unroll
    for (int m = 1; m < 64; m <<= 1) {
        #pragma unroll
        for (int r = 0; r < 8; ++r) e[r] += __shfl_xor(e[r], m, 64);
    }
    const int wave = tid >> 6, lane = tid & 63;
    if (lane == 0) {
        #pragma unroll
        for (int r = 0; r < 8; ++r) red[wave][r] = e[r];
    }
    __syncthreads();
    if (tid < 16) {
        float s = (tid < 8) ? (red[0][tid] + red[1][tid])
                            : (red[2][tid - 8] + red[3][tid - 8]);
        s *= (1.0f / 512.0f);
        re_ws[rbase + tid] = s;
        atomicAdd(sum_ws, s);
    }
}

// ---------------------------------------------------------------------------
// Finalize: scale = mean(re)+1e-8; MDL bits; write all 4 fp32 outputs.
// ---------------------------------------------------------------------------
__global__ __launch_bounds__(256) void fin_kernel(
    const float* __restrict__ re_ws, const float* __restrict__ sum_ws,
    const int* __restrict__ idx_ws, float* __restrict__ out)
{
    const int i = blockIdx.x * 256 + threadIdx.x;
    const float scale = (*sum_ws) * (1.0f / 16384.0f) + 1e-8f;
    const float re = re_ws[i];
    const float lp = -fabsf(re) / scale - logf(2.0f * scale);
    const float eb = -lp * 1.4426950408889634f;
    const float tb = 14.0f + eb;
    const float ratio = 16384.0f / tb;
    out[i]             = re;
    out[16384 + i]     = ratio;
    out[2 * 16384 + i] = tb;
    out[3 * 16384 + i] = (float)idx_ws[i];
}

// ---------------------------------------------------------------------------
extern "C" void kernel_launch(void* const* d_in, const int* in_sizes, int n_in,
                              void* d_out, int out_size, void* d_ws, size_t ws_size,
                              hipStream_t stream)
{
    const float* feat = (const float*)d_in[0];
    const float* W1   = (const float*)d_in[1];
    const float* b1   = (const float*)d_in[2];
    const float* g1   = (const float*)d_in[3];
    const float* be1  = (const float*)d_in[4];
    const float* W2   = (const float*)d_in[5];
    const float* b2   = (const float*)d_in[6];
    const float* cb   = (const float*)d_in[7];
    const float* W3   = (const float*)d_in[8];
    const float* b3   = (const float*)d_in[9];
    const float* g2   = (const float*)d_in[10];
    const float* be2  = (const float*)d_in[11];
    const float* W4   = (const float*)d_in[12];
    const float* b4   = (const float*)d_in[13];

    char* ws = (char*)d_ws;
    const size_t MB = 1u << 20;
    float*    encoded = (float*)ws;                            // 8 MB
    _Float16* xh      = (_Float16*)(ws + 8 * MB);              // 4 MB
    _Float16* xl      = (_Float16*)(ws + 12 * MB);             // 4 MB
    _Float16* cpk     = (_Float16*)(ws + 16 * MB);             // 4 MB (256 x 16KB blobs)
    unsigned* gkey    = (unsigned*)(ws + 24 * MB);             // 16 MB [256][16384]
    float*    Wp1     = (float*)(ws + 40 * MB);                // 512 KB
    float*    Wp2     = (float*)(ws + 40 * MB + (512u << 10)); // 128 KB
    float*    Wp3     = (float*)(ws + 40 * MB + (640u << 10)); // 128 KB
    float*    Wp4     = (float*)(ws + 40 * MB + (768u << 10)); // 512 KB
    float*    cnorm   = (float*)(ws + 41 * MB + (256u << 10)); // 64 KB
    float*    re_ws   = (float*)(ws + 41 * MB + (320u << 10)); // 64 KB
    int*      idx_ws  = (int*)(ws + 41 * MB + (384u << 10));   // 64 KB
    float*    sum_ws  = (float*)(ws + 41 * MB + (448u << 10)); // 4 B

    hipMemsetAsync(sum_ws, 0, sizeof(float), stream);

    hipLaunchKernelGGL(wtrans_kernel, dim3(1280), dim3(256), 0, stream,
                       W1, W2, W3, W4, Wp1, Wp2, Wp3, Wp4);
    hipLaunchKernelGGL(split_kernel, dim3(KN / 8), dim3(256), 0, stream, cb, cpk, cnorm);
    hipLaunchKernelGGL(enc_kernel, dim3(BN / 16), dim3(256), 0, stream,
                       feat, Wp1, b1, g1, be1, Wp2, b2, encoded, xh, xl);
    hipLaunchKernelGGL(mfma_dist_kernel, dim3(512), dim3(256), 0, stream,
                       xh, xl, cpk, cnorm, gkey);
    hipLaunchKernelGGL(refine_kernel, dim3(BN / 16), dim3(256), 0, stream,
                       encoded, cb, cnorm, gkey, idx_ws);
    hipLaunchKernelGGL(dec_kernel, dim3(BN / 16), dim3(256), 0, stream,
                       feat, cb, Wp3, b3, g2, be2, Wp4, b4,
                       idx_ws, re_ws, sum_ws);
    hipLaunchKernelGGL(fin_kernel, dim3(BN / 256), dim3(256), 0, stream,
                       re_ws, sum_ws, idx_ws, (float*)d_out);
}